// Round 2
// baseline (1456.517 us; speedup 1.0000x reference)
//
#include <hip/hip_runtime.h>

#define NN 100000
#define NE 1600000
#define NB_SCAN 391   // ceil(NN/256)

// ---------------- tiny float4 helpers ----------------
__device__ inline float4 f4add(float4 a, float4 b) {
  return make_float4(a.x + b.x, a.y + b.y, a.z + b.z, a.w + b.w);
}

// ---------------- CSR build ----------------

__global__ void count_kernel(const int* __restrict__ dst, int* __restrict__ counts) {
  int i = blockIdx.x * blockDim.x + threadIdx.x;
  int st = gridDim.x * blockDim.x;
  for (; i < NE; i += st) atomicAdd(&counts[dst[i]], 1);
}

__global__ void dinv_kernel(const int* __restrict__ counts, float* __restrict__ dinv) {
  int i = blockIdx.x * blockDim.x + threadIdx.x;
  if (i < NN) {
    float deg = (float)counts[i] + 1.0f;
    dinv[i] = rsqrtf(deg);
  }
}

__global__ void scan1_kernel(const int* __restrict__ counts, int* __restrict__ offsets,
                             int* __restrict__ blocksum) {
  __shared__ int s[256];
  int t = threadIdx.x;
  int i = blockIdx.x * 256 + t;
  int v = (i < NN) ? counts[i] : 0;
  s[t] = v; __syncthreads();
  for (int off = 1; off < 256; off <<= 1) {
    int x = 0;
    if (t >= off) x = s[t - off];
    __syncthreads();
    if (t >= off) s[t] += x;
    __syncthreads();
  }
  if (i < NN) offsets[i] = s[t] - v;          // exclusive within block
  if (t == 255) blocksum[blockIdx.x] = s[255];
}

__global__ void scan2_kernel(const int* __restrict__ blocksum, int* __restrict__ blockpfx,
                             int* __restrict__ offsets) {
  __shared__ int s[512];
  int t = threadIdx.x;
  int v = (t < NB_SCAN) ? blocksum[t] : 0;
  s[t] = v; __syncthreads();
  for (int off = 1; off < 512; off <<= 1) {
    int x = 0;
    if (t >= off) x = s[t - off];
    __syncthreads();
    if (t >= off) s[t] += x;
    __syncthreads();
  }
  if (t < NB_SCAN) blockpfx[t] = s[t] - v;
  if (t == 511) offsets[NN] = s[511];         // == NE
}

__global__ void scan3_kernel(int* __restrict__ offsets, const int* __restrict__ blockpfx,
                             int* __restrict__ cursor) {
  int i = blockIdx.x * 256 + threadIdx.x;
  if (i < NN) {
    int v = offsets[i] + blockpfx[i >> 8];
    offsets[i] = v;
    cursor[i] = v;
  }
}

__global__ void scatter_kernel(const int* __restrict__ src, const int* __restrict__ dst,
                               int* __restrict__ cursor, int* __restrict__ src_s) {
  int i = blockIdx.x * blockDim.x + threadIdx.x;
  int st = gridDim.x * blockDim.x;
  for (; i < NE; i += st) {
    int s = src[i], d = dst[i];
    int pos = atomicAdd(&cursor[d], 1);
    src_s[pos] = s;
  }
}

// ---------------- fold input Linear into layer-0 weight ----------------
// Wc = W_in @ W0  (64x64), bc = b_in @ W0
__global__ void foldw_kernel(const float* __restrict__ W_in, const float* __restrict__ b_in,
                             const float* __restrict__ W0,
                             float* __restrict__ Wc, float* __restrict__ bc) {
  int t = threadIdx.x;
  for (int e = t; e < 4096; e += 256) {
    int i = e >> 6, j = e & 63;
    float s = 0.f;
#pragma unroll
    for (int k = 0; k < 64; ++k) s += W_in[i * 64 + k] * W0[k * 64 + j];
    Wc[e] = s;
  }
  if (t < 64) {
    float s = 0.f;
#pragma unroll
    for (int k = 0; k < 64; ++k) s += b_in[k] * W0[k * 64 + t];
    bc[t] = s;
  }
}

// ---------------- GEMM 64x64 with fused BN-apply+ReLU on input, dinv-scale on output ----
// block = 256 threads (4 waves), 16 rows per block, each thread does 4 rows x 1 col.

__global__ __launch_bounds__(256) void gemm64_kernel(
    const float* __restrict__ x, const float* __restrict__ W, const float* __restrict__ bias,
    const float* __restrict__ gamma, const float* __restrict__ beta,
    const float* __restrict__ meanistd, const float* __restrict__ rowscale,
    float* __restrict__ out) {
  __shared__ float sW[64][64];
  __shared__ float sx[16][64];
  int t = threadIdx.x;
  int col = t & 63;
  int row0 = blockIdx.x * 16;

#pragma unroll
  for (int j = 0; j < 16; ++j) {
    int e = t + 256 * j;              // e & 63 == col
    sW[e >> 6][col] = W[e];
  }
  float g = 1.f, bt = 0.f, mn = 0.f, is = 1.f;
  if (gamma) { g = gamma[col]; bt = beta[col]; mn = meanistd[col]; is = meanistd[64 + col]; }
#pragma unroll
  for (int j = 0; j < 4; ++j) {
    int e = t + 256 * j;
    int r = e >> 6;                   // 0..15
    int grow = row0 + r;
    float v = 0.f;
    if (grow < NN) v = x[(size_t)grow * 64 + col];
    if (gamma) { v = fmaxf(g * (v - mn) * is + bt, 0.f); }
    sx[r][col] = v;
  }
  __syncthreads();

  int wave = t >> 6;
  float acc0 = 0, acc1 = 0, acc2 = 0, acc3 = 0;
#pragma unroll
  for (int k = 0; k < 64; ++k) {
    float wv = sW[k][col];
    acc0 += sx[wave * 4 + 0][k] * wv;
    acc1 += sx[wave * 4 + 1][k] * wv;
    acc2 += sx[wave * 4 + 2][k] * wv;
    acc3 += sx[wave * 4 + 3][k] * wv;
  }
  float bv = bias ? bias[col] : 0.f;
  int r0 = row0 + wave * 4;
#pragma unroll
  for (int r = 0; r < 4; ++r) {
    int grow = r0 + r;
    if (grow < NN) {
      float acc = (r == 0) ? acc0 : (r == 1) ? acc1 : (r == 2) ? acc2 : acc3;
      float rs = rowscale ? rowscale[grow] : 1.f;
      out[(size_t)grow * 64 + col] = (acc + bv) * rs;
    }
  }
}

// ---------------- Edge aggregation (gather) + bias + BN stats ----------------
// 4 nodes per wave (16 lanes x float4 each), edge loop unrolled x4 -> high MLP.
// input hp = h' rows pre-scaled by dinv.  out v = dinv[n]*(sum + h'[n]) + bias.

__global__ __launch_bounds__(256) void agg_kernel(
    const float4* __restrict__ hp, const int* __restrict__ offsets,
    const int* __restrict__ src_s, const float* __restrict__ dinv,
    const float* __restrict__ bvec, float4* __restrict__ h2,
    float* __restrict__ bnacc) {
  int t = threadIdx.x;
  int lane = t & 63;
  int wv = t >> 6;
  int l16 = lane & 15;
  int q = lane >> 4;
  const float4 bias = ((const float4*)bvec)[l16];
  float4 s1 = make_float4(0, 0, 0, 0), s2 = make_float4(0, 0, 0, 0);
  int gw = blockIdx.x * 4 + wv;
  int nw = gridDim.x * 4;
  for (int base = gw * 4; base < NN; base += nw * 4) {
    int n = base + q;
    bool valid = n < NN;
    int beg = 0, end = 0;
    float4 acc = make_float4(0, 0, 0, 0);
    float di = 0.f;
    if (valid) {
      beg = offsets[n];
      end = offsets[n + 1];
      acc = hp[(size_t)n * 16 + l16];     // self term h'[n]
      di = dinv[n];
    }
    int j = beg;
    for (; j + 4 <= end; j += 4) {
      int s0 = src_s[j], s1i = src_s[j + 1], s2i = src_s[j + 2], s3i = src_s[j + 3];
      float4 a0 = hp[(size_t)s0 * 16 + l16];
      float4 a1 = hp[(size_t)s1i * 16 + l16];
      float4 a2 = hp[(size_t)s2i * 16 + l16];
      float4 a3 = hp[(size_t)s3i * 16 + l16];
      acc = f4add(acc, f4add(f4add(a0, a1), f4add(a2, a3)));
    }
    for (; j < end; ++j) {
      acc = f4add(acc, hp[(size_t)src_s[j] * 16 + l16]);
    }
    if (valid) {
      float4 v = make_float4(di * acc.x + bias.x, di * acc.y + bias.y,
                             di * acc.z + bias.z, di * acc.w + bias.w);
      h2[(size_t)n * 16 + l16] = v;
      s1 = f4add(s1, v);
      s2 = f4add(s2, make_float4(v.x * v.x, v.y * v.y, v.z * v.z, v.w * v.w));
    }
  }
  // reduce across the 4 quarters (lanes with equal l16 hold the same channels)
#pragma unroll
  for (int m = 16; m <= 32; m <<= 1) {
    s1.x += __shfl_xor(s1.x, m); s1.y += __shfl_xor(s1.y, m);
    s1.z += __shfl_xor(s1.z, m); s1.w += __shfl_xor(s1.w, m);
    s2.x += __shfl_xor(s2.x, m); s2.y += __shfl_xor(s2.y, m);
    s2.z += __shfl_xor(s2.z, m); s2.w += __shfl_xor(s2.w, m);
  }
  __shared__ float4 ls[4][2][16];
  if (lane < 16) { ls[wv][0][l16] = s1; ls[wv][1][l16] = s2; }
  __syncthreads();
  if (t < 16) {
    float4 a = f4add(f4add(ls[0][0][t], ls[1][0][t]), f4add(ls[2][0][t], ls[3][0][t]));
    float4 b = f4add(f4add(ls[0][1][t], ls[1][1][t]), f4add(ls[2][1][t], ls[3][1][t]));
    atomicAdd(&bnacc[t * 4 + 0], a.x);
    atomicAdd(&bnacc[t * 4 + 1], a.y);
    atomicAdd(&bnacc[t * 4 + 2], a.z);
    atomicAdd(&bnacc[t * 4 + 3], a.w);
    atomicAdd(&bnacc[64 + t * 4 + 0], b.x);
    atomicAdd(&bnacc[64 + t * 4 + 1], b.y);
    atomicAdd(&bnacc[64 + t * 4 + 2], b.z);
    atomicAdd(&bnacc[64 + t * 4 + 3], b.w);
  }
}

__global__ void bn_finalize_kernel(const float* __restrict__ bnacc, float* __restrict__ bnpar) {
  int c = threadIdx.x;  // 64 threads
  float mean = bnacc[c] * (1.0f / NN);
  float var = bnacc[64 + c] * (1.0f / NN) - mean * mean;
  bnpar[c] = mean;
  bnpar[64 + c] = rsqrtf(var + 1e-5f);
}

// ---------------- Output MLP: BN-apply -> Linear(64,128)+ReLU -> Linear(128,1) ----------------

__global__ __launch_bounds__(256) void out_kernel(
    const float* __restrict__ x,
    const float* __restrict__ gamma, const float* __restrict__ beta,
    const float* __restrict__ meanistd,
    const float* __restrict__ W1, const float* __restrict__ b1,
    const float* __restrict__ W2, const float* __restrict__ b2,
    float* __restrict__ out) {
  __shared__ float sW1[64][128];
  __shared__ float sW2[128];
  int t = threadIdx.x;
#pragma unroll
  for (int j = 0; j < 32; ++j) {
    int e = t + 256 * j;
    sW1[e >> 7][e & 127] = W1[e];
  }
  if (t < 128) sW2[t] = W2[t];
  __syncthreads();

  int lane = t & 63, wv = t >> 6;
  float g = gamma[lane], bt = beta[lane], mn = meanistd[lane], is = meanistd[64 + lane];
  float b1a = b1[lane], b1b = b1[64 + lane];
  float w2a = sW2[lane], w2b = sW2[64 + lane];
  float bias2 = b2[0];
  int nw = gridDim.x * 4;
  for (int row = blockIdx.x * 4 + wv; row < NN; row += nw) {
    float xv = x[(size_t)row * 64 + lane];
    xv = g * (xv - mn) * is + bt;   // last-layer BN, no ReLU
    float acc0 = 0, acc1 = 0;
#pragma unroll
    for (int k = 0; k < 64; ++k) {
      float xk = __shfl(xv, k);
      acc0 += xk * sW1[k][lane];
      acc1 += xk * sW1[k][64 + lane];
    }
    acc0 = fmaxf(acc0 + b1a, 0.f);
    acc1 = fmaxf(acc1 + b1b, 0.f);
    float p = acc0 * w2a + acc1 * w2b;
#pragma unroll
    for (int off = 32; off > 0; off >>= 1) p += __shfl_down(p, off);
    if (lane == 0) out[row] = p + bias2;
  }
}

// ---------------- launch ----------------

extern "C" void kernel_launch(void* const* d_in, const int* in_sizes, int n_in,
                              void* d_out, int out_size, void* d_ws, size_t ws_size,
                              hipStream_t stream) {
  const float* X = (const float*)d_in[0];
  const int* edge = (const int*)d_in[1];
  const int* esrc = edge;
  const int* edst = edge + NE;
  const float* W_in = (const float*)d_in[2];
  const float* b_in = (const float*)d_in[3];
  const float* Ws = (const float*)d_in[4];
  const float* bs = (const float*)d_in[5];
  const float* gammas = (const float*)d_in[6];
  const float* betas = (const float*)d_in[7];
  const float* W1 = (const float*)d_in[8];
  const float* b1 = (const float*)d_in[9];
  const float* W2 = (const float*)d_in[10];
  const float* b2 = (const float*)d_in[11];
  float* out = (float*)d_out;

  char* base = (char*)d_ws;
  size_t o = 0;
  auto alloc = [&](size_t bytes) {
    o = (o + 255) & ~(size_t)255;
    void* p = base + o;
    o += bytes;
    return p;
  };
  int* counts = (int*)alloc((size_t)NN * 4);
  int* offsets = (int*)alloc((size_t)(NN + 1) * 4);
  int* cursor = (int*)alloc((size_t)NN * 4);
  int* blocksum = (int*)alloc(512 * 4);
  int* blockpfx = (int*)alloc(512 * 4);
  int* src_s = (int*)alloc((size_t)NE * 4);
  float* dinv = (float*)alloc((size_t)NN * 4);
  float* bufA = (float*)alloc((size_t)NN * 64 * 4);
  float* bufB = (float*)alloc((size_t)NN * 64 * 4);
  float* hbuf = (float*)alloc((size_t)NN * 64 * 4);
  float* bnacc = (float*)alloc(3 * 128 * 4);
  float* bnpar = (float*)alloc(3 * 128 * 4);
  float* Wc = (float*)alloc(4096 * 4);
  float* bc = (float*)alloc(64 * 4);

  hipMemsetAsync(counts, 0, (size_t)NN * 4, stream);
  hipMemsetAsync(bnacc, 0, 3 * 128 * 4, stream);

  foldw_kernel<<<1, 256, 0, stream>>>(W_in, b_in, Ws, Wc, bc);
  count_kernel<<<2048, 256, 0, stream>>>(edst, counts);
  dinv_kernel<<<(NN + 255) / 256, 256, 0, stream>>>(counts, dinv);
  scan1_kernel<<<NB_SCAN, 256, 0, stream>>>(counts, offsets, blocksum);
  scan2_kernel<<<1, 512, 0, stream>>>(blocksum, blockpfx, offsets);
  scan3_kernel<<<NB_SCAN, 256, 0, stream>>>(offsets, blockpfx, cursor);
  scatter_kernel<<<2048, 256, 0, stream>>>(esrc, edst, cursor, src_s);

  const int GEMM_GRID = (NN + 15) / 16;
  float* xbufs[2] = {bufA, bufB};
  const float* xcur = nullptr;
  for (int i = 0; i < 3; ++i) {
    if (i == 0) {
      // folded: hbuf = (X @ Wc + bc) * dinv
      gemm64_kernel<<<GEMM_GRID, 256, 0, stream>>>(X, Wc, bc, nullptr, nullptr, nullptr,
                                                   dinv, hbuf);
    } else {
      gemm64_kernel<<<GEMM_GRID, 256, 0, stream>>>(xcur, Ws + (size_t)i * 64 * 64, nullptr,
                                                   gammas + (size_t)(i - 1) * 64,
                                                   betas + (size_t)(i - 1) * 64,
                                                   bnpar + (size_t)(i - 1) * 128,
                                                   dinv, hbuf);
    }
    float* xnext = xbufs[i & 1];
    agg_kernel<<<2048, 256, 0, stream>>>((const float4*)hbuf, offsets, src_s, dinv,
                                         bs + (size_t)i * 64, (float4*)xnext,
                                         bnacc + (size_t)i * 128);
    bn_finalize_kernel<<<1, 64, 0, stream>>>(bnacc + (size_t)i * 128, bnpar + (size_t)i * 128);
    xcur = xnext;
  }
  // xcur holds layer-2 pre-BN output
  out_kernel<<<2048, 256, 0, stream>>>(xcur, gammas + 2 * 64, betas + 2 * 64, bnpar + 2 * 128,
                                       W1, b1, W2, b2, out);
}

// Round 3
// 1150.467 us; speedup vs baseline: 1.2660x; 1.2660x over previous
//
#include <hip/hip_runtime.h>

#define NN 100000
#define NE 1600000
#define NB_SCAN 391   // ceil(NN/256)

// ---------------- CSR build ----------------

__global__ void count_kernel(const int* __restrict__ dst, int* __restrict__ counts) {
  int i = blockIdx.x * blockDim.x + threadIdx.x;
  int st = gridDim.x * blockDim.x;
  for (; i < NE; i += st) atomicAdd(&counts[dst[i]], 1);
}

__global__ void dinv_kernel(const int* __restrict__ counts, float* __restrict__ dinv) {
  int i = blockIdx.x * blockDim.x + threadIdx.x;
  if (i < NN) {
    float deg = (float)counts[i] + 1.0f;
    dinv[i] = rsqrtf(deg);
  }
}

__global__ void scan1_kernel(const int* __restrict__ counts, int* __restrict__ offsets,
                             int* __restrict__ blocksum) {
  __shared__ int s[256];
  int t = threadIdx.x;
  int i = blockIdx.x * 256 + t;
  int v = (i < NN) ? counts[i] : 0;
  s[t] = v; __syncthreads();
  for (int off = 1; off < 256; off <<= 1) {
    int x = 0;
    if (t >= off) x = s[t - off];
    __syncthreads();
    if (t >= off) s[t] += x;
    __syncthreads();
  }
  if (i < NN) offsets[i] = s[t] - v;          // exclusive within block
  if (t == 255) blocksum[blockIdx.x] = s[255];
}

__global__ void scan2_kernel(const int* __restrict__ blocksum, int* __restrict__ blockpfx,
                             int* __restrict__ offsets) {
  __shared__ int s[512];
  int t = threadIdx.x;
  int v = (t < NB_SCAN) ? blocksum[t] : 0;
  s[t] = v; __syncthreads();
  for (int off = 1; off < 512; off <<= 1) {
    int x = 0;
    if (t >= off) x = s[t - off];
    __syncthreads();
    if (t >= off) s[t] += x;
    __syncthreads();
  }
  if (t < NB_SCAN) blockpfx[t] = s[t] - v;
  if (t == 511) offsets[NN] = s[511];         // == NE
}

__global__ void scan3_kernel(int* __restrict__ offsets, const int* __restrict__ blockpfx,
                             int* __restrict__ cursor) {
  int i = blockIdx.x * 256 + threadIdx.x;
  if (i < NN) {
    int v = offsets[i] + blockpfx[i >> 8];
    offsets[i] = v;
    cursor[i] = v;
  }
}

__global__ void scatter_kernel(const int* __restrict__ src, const int* __restrict__ dst,
                               int* __restrict__ cursor, int* __restrict__ src_s) {
  int i = blockIdx.x * blockDim.x + threadIdx.x;
  int st = gridDim.x * blockDim.x;
  for (; i < NE; i += st) {
    int s = src[i], d = dst[i];
    int pos = atomicAdd(&cursor[d], 1);
    src_s[pos] = s;
  }
}

// ---------------- GEMM 64x64 (input Linear only), dinv row-scale on output ----------------

__global__ __launch_bounds__(256) void gemm64_kernel(
    const float* __restrict__ x, const float* __restrict__ W, const float* __restrict__ bias,
    const float* __restrict__ rowscale, float* __restrict__ out) {
  __shared__ float sW[64][64];
  __shared__ float sx[16][64];
  int t = threadIdx.x;
  int col = t & 63;
  int row0 = blockIdx.x * 16;

#pragma unroll
  for (int j = 0; j < 16; ++j) {
    int e = t + 256 * j;              // e & 63 == col
    sW[e >> 6][col] = W[e];
  }
#pragma unroll
  for (int j = 0; j < 4; ++j) {
    int e = t + 256 * j;
    int r = e >> 6;                   // 0..15
    int grow = row0 + r;
    float v = 0.f;
    if (grow < NN) v = x[(size_t)grow * 64 + col];
    sx[r][col] = v;
  }
  __syncthreads();

  int wave = t >> 6;
  float acc0 = 0, acc1 = 0, acc2 = 0, acc3 = 0;
#pragma unroll
  for (int k = 0; k < 64; ++k) {
    float wv = sW[k][col];
    acc0 += sx[wave * 4 + 0][k] * wv;
    acc1 += sx[wave * 4 + 1][k] * wv;
    acc2 += sx[wave * 4 + 2][k] * wv;
    acc3 += sx[wave * 4 + 3][k] * wv;
  }
  float bv = bias[col];
  int r0 = row0 + wave * 4;
#pragma unroll
  for (int r = 0; r < 4; ++r) {
    int grow = r0 + r;
    if (grow < NN) {
      float acc = (r == 0) ? acc0 : (r == 1) ? acc1 : (r == 2) ? acc2 : acc3;
      out[(size_t)grow * 64 + col] = (acc + bv) * rowscale[grow];
    }
  }
}

// ---------------- Fused aggregation + 64x64 matvec + bias + BN stats ----------------
// One node per wave (lane = channel). xp rows are pre-scaled by dinv (and BN+ReLU'd
// for layers >0 via bnx_kernel).  h2[n] = (dinv[n] * (sum_src xp[src] + xp[n])) @ W + b.

__global__ __launch_bounds__(256) void agg_mv_kernel(
    const float* __restrict__ xp, const int* __restrict__ offsets,
    const int* __restrict__ src_s, const float* __restrict__ dinv,
    const float* __restrict__ W, const float* __restrict__ bvec,
    float* __restrict__ h2, float* __restrict__ bnacc) {
  __shared__ float sW[64][64];
  __shared__ float ls[4][2][64];
  int t = threadIdx.x;
  int lane = t & 63;
  int wv = t >> 6;

#pragma unroll
  for (int j = 0; j < 16; ++j) {
    int e = t + 256 * j;
    sW[e >> 6][lane] = W[e];          // e & 63 == lane
  }
  __syncthreads();

  float bias = bvec[lane];
  float s1 = 0.f, s2 = 0.f;
  int gw = blockIdx.x * 4 + wv;
  int nw = gridDim.x * 4;
  for (int n = gw; n < NN; n += nw) {
    int beg = offsets[n], end = offsets[n + 1];
    float acc0 = xp[(size_t)n * 64 + lane];   // self term
    float acc1 = 0.f, acc2 = 0.f, acc3 = 0.f;
    int j = beg;
    for (; j + 4 <= end; j += 4) {
      int s0 = src_s[j], s1i = src_s[j + 1], s2i = src_s[j + 2], s3i = src_s[j + 3];
      float v0 = xp[(size_t)s0 * 64 + lane];
      float v1 = xp[(size_t)s1i * 64 + lane];
      float v2 = xp[(size_t)s2i * 64 + lane];
      float v3 = xp[(size_t)s3i * 64 + lane];
      acc0 += v0; acc1 += v1; acc2 += v2; acc3 += v3;
    }
    for (; j < end; ++j) acc0 += xp[(size_t)src_s[j] * 64 + lane];
    float total = ((acc0 + acc1) + (acc2 + acc3)) * dinv[n];

    // matvec: v[lane] = sum_k total_k * W[k][lane]
    float v = bias;
#pragma unroll
    for (int k = 0; k < 64; ++k) {
      float xk = __shfl(total, k);
      v += xk * sW[k][lane];
    }
    h2[(size_t)n * 64 + lane] = v;
    s1 += v;
    s2 += v * v;
  }
  ls[wv][0][lane] = s1;
  ls[wv][1][lane] = s2;
  __syncthreads();
  if (wv == 0) {
    float a = ls[0][0][lane] + ls[1][0][lane] + ls[2][0][lane] + ls[3][0][lane];
    float b = ls[0][1][lane] + ls[1][1][lane] + ls[2][1][lane] + ls[3][1][lane];
    atomicAdd(&bnacc[lane], a);
    atomicAdd(&bnacc[64 + lane], b);
  }
}

__global__ void bn_finalize_kernel(const float* __restrict__ bnacc, float* __restrict__ bnpar) {
  int c = threadIdx.x;  // 64 threads
  float mean = bnacc[c] * (1.0f / NN);
  float var = bnacc[64 + c] * (1.0f / NN) - mean * mean;
  bnpar[c] = mean;
  bnpar[64 + c] = rsqrtf(var + 1e-5f);
}

// ---------------- BN-apply + ReLU + dinv row-scale (elementwise, float4) ----------------

__global__ __launch_bounds__(256) void bnx_kernel(
    const float4* __restrict__ h2, const float* __restrict__ bnpar,
    const float* __restrict__ gamma, const float* __restrict__ beta,
    const float* __restrict__ dinv, float4* __restrict__ xp) {
  int i = blockIdx.x * blockDim.x + threadIdx.x;
  int st = gridDim.x * blockDim.x;
  const float4* g4 = (const float4*)gamma;
  const float4* b4 = (const float4*)beta;
  const float4* m4 = (const float4*)bnpar;
  const float4* i4 = (const float4*)(bnpar + 64);
  for (; i < NN * 16; i += st) {
    int row = i >> 4, c = i & 15;
    float4 v = h2[i];
    float4 g = g4[c], bt = b4[c], mn = m4[c], is = i4[c];
    float di = dinv[row];
    v.x = di * fmaxf(g.x * (v.x - mn.x) * is.x + bt.x, 0.f);
    v.y = di * fmaxf(g.y * (v.y - mn.y) * is.y + bt.y, 0.f);
    v.z = di * fmaxf(g.z * (v.z - mn.z) * is.z + bt.z, 0.f);
    v.w = di * fmaxf(g.w * (v.w - mn.w) * is.w + bt.w, 0.f);
    xp[i] = v;
  }
}

// ---------------- Output MLP: BN-apply -> Linear(64,128)+ReLU -> Linear(128,1) ----------------

__global__ __launch_bounds__(256) void out_kernel(
    const float* __restrict__ x,
    const float* __restrict__ gamma, const float* __restrict__ beta,
    const float* __restrict__ meanistd,
    const float* __restrict__ W1, const float* __restrict__ b1,
    const float* __restrict__ W2, const float* __restrict__ b2,
    float* __restrict__ out) {
  __shared__ float sW1[64][128];
  __shared__ float sW2[128];
  int t = threadIdx.x;
#pragma unroll
  for (int j = 0; j < 32; ++j) {
    int e = t + 256 * j;
    sW1[e >> 7][e & 127] = W1[e];
  }
  if (t < 128) sW2[t] = W2[t];
  __syncthreads();

  int lane = t & 63, wv = t >> 6;
  float g = gamma[lane], bt = beta[lane], mn = meanistd[lane], is = meanistd[64 + lane];
  float b1a = b1[lane], b1b = b1[64 + lane];
  float w2a = sW2[lane], w2b = sW2[64 + lane];
  float bias2 = b2[0];
  int nw = gridDim.x * 4;
  for (int row = blockIdx.x * 4 + wv; row < NN; row += nw) {
    float xv = x[(size_t)row * 64 + lane];
    xv = g * (xv - mn) * is + bt;   // last-layer BN, no ReLU
    float acc0 = 0, acc1 = 0;
#pragma unroll
    for (int k = 0; k < 64; ++k) {
      float xk = __shfl(xv, k);
      acc0 += xk * sW1[k][lane];
      acc1 += xk * sW1[k][64 + lane];
    }
    acc0 = fmaxf(acc0 + b1a, 0.f);
    acc1 = fmaxf(acc1 + b1b, 0.f);
    float p = acc0 * w2a + acc1 * w2b;
#pragma unroll
    for (int off = 32; off > 0; off >>= 1) p += __shfl_down(p, off);
    if (lane == 0) out[row] = p + bias2;
  }
}

// ---------------- launch ----------------

extern "C" void kernel_launch(void* const* d_in, const int* in_sizes, int n_in,
                              void* d_out, int out_size, void* d_ws, size_t ws_size,
                              hipStream_t stream) {
  const float* X = (const float*)d_in[0];
  const int* edge = (const int*)d_in[1];
  const int* esrc = edge;
  const int* edst = edge + NE;
  const float* W_in = (const float*)d_in[2];
  const float* b_in = (const float*)d_in[3];
  const float* Ws = (const float*)d_in[4];
  const float* bs = (const float*)d_in[5];
  const float* gammas = (const float*)d_in[6];
  const float* betas = (const float*)d_in[7];
  const float* W1 = (const float*)d_in[8];
  const float* b1 = (const float*)d_in[9];
  const float* W2 = (const float*)d_in[10];
  const float* b2 = (const float*)d_in[11];
  float* out = (float*)d_out;

  char* base = (char*)d_ws;
  size_t o = 0;
  auto alloc = [&](size_t bytes) {
    o = (o + 255) & ~(size_t)255;
    void* p = base + o;
    o += bytes;
    return p;
  };
  int* counts = (int*)alloc((size_t)NN * 4);
  int* offsets = (int*)alloc((size_t)(NN + 1) * 4);
  int* cursor = (int*)alloc((size_t)NN * 4);
  int* blocksum = (int*)alloc(512 * 4);
  int* blockpfx = (int*)alloc(512 * 4);
  int* src_s = (int*)alloc((size_t)NE * 4);
  float* dinv = (float*)alloc((size_t)NN * 4);
  float* bufA = (float*)alloc((size_t)NN * 64 * 4);
  float* bufB = (float*)alloc((size_t)NN * 64 * 4);
  float* bufC = (float*)alloc((size_t)NN * 64 * 4);
  float* bnacc = (float*)alloc(3 * 128 * 4);
  float* bnpar = (float*)alloc(3 * 128 * 4);

  hipMemsetAsync(counts, 0, (size_t)NN * 4, stream);
  hipMemsetAsync(bnacc, 0, 3 * 128 * 4, stream);

  count_kernel<<<2048, 256, 0, stream>>>(edst, counts);
  dinv_kernel<<<(NN + 255) / 256, 256, 0, stream>>>(counts, dinv);
  scan1_kernel<<<NB_SCAN, 256, 0, stream>>>(counts, offsets, blocksum);
  scan2_kernel<<<1, 512, 0, stream>>>(blocksum, blockpfx, offsets);
  scan3_kernel<<<NB_SCAN, 256, 0, stream>>>(offsets, blockpfx, cursor);
  scatter_kernel<<<2048, 256, 0, stream>>>(esrc, edst, cursor, src_s);

  const int GEMM_GRID = (NN + 15) / 16;
  // x0' = (X @ W_in + b_in) * dinv   (pre-scaled input to layer-0 aggregation)
  gemm64_kernel<<<GEMM_GRID, 256, 0, stream>>>(X, W_in, b_in, dinv, bufA);

  // Layer 0: bufA -> h2 in bufB
  agg_mv_kernel<<<2048, 256, 0, stream>>>(bufA, offsets, src_s, dinv, Ws, bs, bufB, bnacc);
  bn_finalize_kernel<<<1, 64, 0, stream>>>(bnacc, bnpar);
  bnx_kernel<<<2048, 256, 0, stream>>>((const float4*)bufB, bnpar, gammas, betas, dinv,
                                       (float4*)bufC);
  // Layer 1: bufC -> h2 in bufA
  agg_mv_kernel<<<2048, 256, 0, stream>>>(bufC, offsets, src_s, dinv, Ws + 4096, bs + 64,
                                          bufA, bnacc + 128);
  bn_finalize_kernel<<<1, 64, 0, stream>>>(bnacc + 128, bnpar + 128);
  bnx_kernel<<<2048, 256, 0, stream>>>((const float4*)bufA, bnpar + 128, gammas + 64,
                                       betas + 64, dinv, (float4*)bufB);
  // Layer 2: bufB -> h2 in bufC
  agg_mv_kernel<<<2048, 256, 0, stream>>>(bufB, offsets, src_s, dinv, Ws + 8192, bs + 128,
                                          bufC, bnacc + 256);
  bn_finalize_kernel<<<1, 64, 0, stream>>>(bnacc + 256, bnpar + 256);

  out_kernel<<<2048, 256, 0, stream>>>(bufC, gammas + 128, betas + 128, bnpar + 256,
                                       W1, b1, W2, b2, out);
}

// Round 4
// 917.825 us; speedup vs baseline: 1.5869x; 1.2535x over previous
//
#include <hip/hip_runtime.h>

#define NN 100000
#define NE 1600000
#define NB_SCAN 391   // ceil(NN/256)

// ---------------- CSR build ----------------

// pass 1: histogram + per-edge rank (coalesced write), atomics on counts only
__global__ void count_rank_kernel(const int* __restrict__ dst, int* __restrict__ counts,
                                  int* __restrict__ rank) {
  int i = blockIdx.x * blockDim.x + threadIdx.x;
  int st = gridDim.x * blockDim.x;
  for (; i < NE; i += st) rank[i] = atomicAdd(&counts[dst[i]], 1);
}

__global__ void dinv_kernel(const int* __restrict__ counts, float* __restrict__ dinv) {
  int i = blockIdx.x * blockDim.x + threadIdx.x;
  if (i < NN) {
    float deg = (float)counts[i] + 1.0f;
    dinv[i] = rsqrtf(deg);
  }
}

__global__ void scan1_kernel(const int* __restrict__ counts, int* __restrict__ offsets,
                             int* __restrict__ blocksum) {
  __shared__ int s[256];
  int t = threadIdx.x;
  int i = blockIdx.x * 256 + t;
  int v = (i < NN) ? counts[i] : 0;
  s[t] = v; __syncthreads();
  for (int off = 1; off < 256; off <<= 1) {
    int x = 0;
    if (t >= off) x = s[t - off];
    __syncthreads();
    if (t >= off) s[t] += x;
    __syncthreads();
  }
  if (i < NN) offsets[i] = s[t] - v;          // exclusive within block
  if (t == 255) blocksum[blockIdx.x] = s[255];
}

__global__ void scan2_kernel(const int* __restrict__ blocksum, int* __restrict__ blockpfx,
                             int* __restrict__ offsets) {
  __shared__ int s[512];
  int t = threadIdx.x;
  int v = (t < NB_SCAN) ? blocksum[t] : 0;
  s[t] = v; __syncthreads();
  for (int off = 1; off < 512; off <<= 1) {
    int x = 0;
    if (t >= off) x = s[t - off];
    __syncthreads();
    if (t >= off) s[t] += x;
    __syncthreads();
  }
  if (t < NB_SCAN) blockpfx[t] = s[t] - v;
  if (t == 511) offsets[NN] = s[511];         // == NE
}

__global__ void scan3_kernel(int* __restrict__ offsets, const int* __restrict__ blockpfx) {
  int i = blockIdx.x * 256 + threadIdx.x;
  if (i < NN) offsets[i] += blockpfx[i >> 8];
}

// pass 2: atomic-free scatter using precomputed ranks
__global__ void scatter_kernel(const int* __restrict__ src, const int* __restrict__ dst,
                               const int* __restrict__ offsets, const int* __restrict__ rank,
                               int* __restrict__ src_s) {
  int i = blockIdx.x * blockDim.x + threadIdx.x;
  int st = gridDim.x * blockDim.x;
  for (; i < NE; i += st) {
    int d = dst[i];
    src_s[offsets[d] + rank[i]] = src[i];
  }
}

// ---------------- fold input Linear into layer-0 weight ----------------
// Wc = W_in @ W0  (64x64), bc = b_in @ W0
__global__ void foldw_kernel(const float* __restrict__ W_in, const float* __restrict__ b_in,
                             const float* __restrict__ W0,
                             float* __restrict__ Wc, float* __restrict__ bc) {
  int t = threadIdx.x;
  for (int e = t; e < 4096; e += 256) {
    int i = e >> 6, j = e & 63;
    float s = 0.f;
#pragma unroll
    for (int k = 0; k < 64; ++k) s += W_in[i * 64 + k] * W0[k * 64 + j];
    Wc[e] = s;
  }
  if (t < 64) {
    float s = 0.f;
#pragma unroll
    for (int k = 0; k < 64; ++k) s += b_in[k] * W0[k * 64 + t];
    bc[t] = s;
  }
}

// ---------------- GEMM 64x64, fused BN-apply+ReLU on input, dinv row-scale on output ----

__global__ __launch_bounds__(256) void gemm64_kernel(
    const float* __restrict__ x, const float* __restrict__ W, const float* __restrict__ bias,
    const float* __restrict__ gamma, const float* __restrict__ beta,
    const float* __restrict__ meanistd, const float* __restrict__ rowscale,
    float* __restrict__ out) {
  __shared__ float sW[64][64];
  __shared__ float sx[16][64];
  int t = threadIdx.x;
  int col = t & 63;
  int row0 = blockIdx.x * 16;

#pragma unroll
  for (int j = 0; j < 16; ++j) {
    int e = t + 256 * j;              // e & 63 == col
    sW[e >> 6][col] = W[e];
  }
  float g = 1.f, bt = 0.f, mn = 0.f, is = 1.f;
  if (gamma) { g = gamma[col]; bt = beta[col]; mn = meanistd[col]; is = meanistd[64 + col]; }
#pragma unroll
  for (int j = 0; j < 4; ++j) {
    int e = t + 256 * j;
    int r = e >> 6;                   // 0..15
    int grow = row0 + r;
    float v = 0.f;
    if (grow < NN) v = x[(size_t)grow * 64 + col];
    if (gamma) v = fmaxf(g * (v - mn) * is + bt, 0.f);
    sx[r][col] = v;
  }
  __syncthreads();

  int wave = t >> 6;
  float acc0 = 0, acc1 = 0, acc2 = 0, acc3 = 0;
#pragma unroll
  for (int k = 0; k < 64; ++k) {
    float wv = sW[k][col];
    acc0 += sx[wave * 4 + 0][k] * wv;
    acc1 += sx[wave * 4 + 1][k] * wv;
    acc2 += sx[wave * 4 + 2][k] * wv;
    acc3 += sx[wave * 4 + 3][k] * wv;
  }
  float bv = bias ? bias[col] : 0.f;
  int r0 = row0 + wave * 4;
#pragma unroll
  for (int r = 0; r < 4; ++r) {
    int grow = r0 + r;
    if (grow < NN) {
      float acc = (r == 0) ? acc0 : (r == 1) ? acc1 : (r == 2) ? acc2 : acc3;
      out[(size_t)grow * 64 + col] = (acc + bv) * rowscale[grow];
    }
  }
}

// ---------------- Edge aggregation + bias + BN stats ----------------
// One node per wave (lane = channel), edge loop unrolled x8 into 8 independent
// accumulators -> 8 gathers in flight per wave at VGPR<64 (full occupancy).
// xp rows pre-scaled by dinv.  h2[n] = dinv[n]*(sum_src xp[src] + xp[n]) + b.

__global__ __launch_bounds__(256) void agg_kernel(
    const float* __restrict__ xp, const int* __restrict__ offsets,
    const int* __restrict__ src_s, const float* __restrict__ dinv,
    const float* __restrict__ bvec, float* __restrict__ h2,
    float* __restrict__ bnacc) {
  int t = threadIdx.x;
  int lane = t & 63;
  int wv = t >> 6;
  float bias = bvec[lane];
  float s1 = 0.f, s2 = 0.f;
  int gw = blockIdx.x * 4 + wv;
  int nw = gridDim.x * 4;
  for (int n = gw; n < NN; n += nw) {
    int beg = offsets[n], end = offsets[n + 1];
    float a0 = xp[(size_t)n * 64 + lane];   // self term
    float a1 = 0.f, a2 = 0.f, a3 = 0.f, a4 = 0.f, a5 = 0.f, a6 = 0.f, a7 = 0.f;
    int j = beg;
    for (; j + 8 <= end; j += 8) {
      int s0 = src_s[j + 0], s1i = src_s[j + 1], s2i = src_s[j + 2], s3i = src_s[j + 3];
      int s4 = src_s[j + 4], s5i = src_s[j + 5], s6i = src_s[j + 6], s7i = src_s[j + 7];
      a0 += xp[(size_t)s0 * 64 + lane];
      a1 += xp[(size_t)s1i * 64 + lane];
      a2 += xp[(size_t)s2i * 64 + lane];
      a3 += xp[(size_t)s3i * 64 + lane];
      a4 += xp[(size_t)s4 * 64 + lane];
      a5 += xp[(size_t)s5i * 64 + lane];
      a6 += xp[(size_t)s6i * 64 + lane];
      a7 += xp[(size_t)s7i * 64 + lane];
    }
    for (; j < end; ++j) a0 += xp[(size_t)src_s[j] * 64 + lane];
    float tot = (((a0 + a1) + (a2 + a3)) + ((a4 + a5) + (a6 + a7))) * dinv[n];
    float v = tot + bias;
    h2[(size_t)n * 64 + lane] = v;
    s1 += v;
    s2 += v * v;
  }
  __shared__ float ls[4][2][64];
  ls[wv][0][lane] = s1;
  ls[wv][1][lane] = s2;
  __syncthreads();
  if (wv == 0) {
    float a = ls[0][0][lane] + ls[1][0][lane] + ls[2][0][lane] + ls[3][0][lane];
    float b = ls[0][1][lane] + ls[1][1][lane] + ls[2][1][lane] + ls[3][1][lane];
    atomicAdd(&bnacc[lane], a);
    atomicAdd(&bnacc[64 + lane], b);
  }
}

__global__ void bn_finalize_kernel(const float* __restrict__ bnacc, float* __restrict__ bnpar) {
  int c = threadIdx.x;  // 64 threads
  float mean = bnacc[c] * (1.0f / NN);
  float var = bnacc[64 + c] * (1.0f / NN) - mean * mean;
  bnpar[c] = mean;
  bnpar[64 + c] = rsqrtf(var + 1e-5f);
}

// ---------------- Output MLP: BN-apply -> Linear(64,128)+ReLU -> Linear(128,1) ----------------

__global__ __launch_bounds__(256) void out_kernel(
    const float* __restrict__ x,
    const float* __restrict__ gamma, const float* __restrict__ beta,
    const float* __restrict__ meanistd,
    const float* __restrict__ W1, const float* __restrict__ b1,
    const float* __restrict__ W2, const float* __restrict__ b2,
    float* __restrict__ out) {
  __shared__ float sW1[64][128];
  __shared__ float sW2[128];
  int t = threadIdx.x;
#pragma unroll
  for (int j = 0; j < 32; ++j) {
    int e = t + 256 * j;
    sW1[e >> 7][e & 127] = W1[e];
  }
  if (t < 128) sW2[t] = W2[t];
  __syncthreads();

  int lane = t & 63, wv = t >> 6;
  float g = gamma[lane], bt = beta[lane], mn = meanistd[lane], is = meanistd[64 + lane];
  float b1a = b1[lane], b1b = b1[64 + lane];
  float w2a = sW2[lane], w2b = sW2[64 + lane];
  float bias2 = b2[0];
  int nw = gridDim.x * 4;
  for (int row = blockIdx.x * 4 + wv; row < NN; row += nw) {
    float xv = x[(size_t)row * 64 + lane];
    xv = g * (xv - mn) * is + bt;   // last-layer BN, no ReLU
    float acc0 = 0, acc1 = 0;
#pragma unroll
    for (int k = 0; k < 64; ++k) {
      float xk = __shfl(xv, k);
      acc0 += xk * sW1[k][lane];
      acc1 += xk * sW1[k][64 + lane];
    }
    acc0 = fmaxf(acc0 + b1a, 0.f);
    acc1 = fmaxf(acc1 + b1b, 0.f);
    float p = acc0 * w2a + acc1 * w2b;
#pragma unroll
    for (int off = 32; off > 0; off >>= 1) p += __shfl_down(p, off);
    if (lane == 0) out[row] = p + bias2;
  }
}

// ---------------- launch ----------------

extern "C" void kernel_launch(void* const* d_in, const int* in_sizes, int n_in,
                              void* d_out, int out_size, void* d_ws, size_t ws_size,
                              hipStream_t stream) {
  const float* X = (const float*)d_in[0];
  const int* edge = (const int*)d_in[1];
  const int* esrc = edge;
  const int* edst = edge + NE;
  const float* W_in = (const float*)d_in[2];
  const float* b_in = (const float*)d_in[3];
  const float* Ws = (const float*)d_in[4];
  const float* bs = (const float*)d_in[5];
  const float* gammas = (const float*)d_in[6];
  const float* betas = (const float*)d_in[7];
  const float* W1 = (const float*)d_in[8];
  const float* b1 = (const float*)d_in[9];
  const float* W2 = (const float*)d_in[10];
  const float* b2 = (const float*)d_in[11];
  float* out = (float*)d_out;

  char* base = (char*)d_ws;
  size_t o = 0;
  auto alloc = [&](size_t bytes) {
    o = (o + 255) & ~(size_t)255;
    void* p = base + o;
    o += bytes;
    return p;
  };
  int* counts = (int*)alloc((size_t)NN * 4);
  int* offsets = (int*)alloc((size_t)(NN + 1) * 4);
  int* blocksum = (int*)alloc(512 * 4);
  int* blockpfx = (int*)alloc(512 * 4);
  int* rank = (int*)alloc((size_t)NE * 4);
  int* src_s = (int*)alloc((size_t)NE * 4);
  float* dinv = (float*)alloc((size_t)NN * 4);
  float* bufA = (float*)alloc((size_t)NN * 64 * 4);
  float* bufB = (float*)alloc((size_t)NN * 64 * 4);
  float* hbuf = (float*)alloc((size_t)NN * 64 * 4);
  float* bnacc = (float*)alloc(3 * 128 * 4);
  float* bnpar = (float*)alloc(3 * 128 * 4);
  float* Wc = (float*)alloc(4096 * 4);
  float* bc = (float*)alloc(64 * 4);

  hipMemsetAsync(counts, 0, (size_t)NN * 4, stream);
  hipMemsetAsync(bnacc, 0, 3 * 128 * 4, stream);

  foldw_kernel<<<1, 256, 0, stream>>>(W_in, b_in, Ws, Wc, bc);
  count_rank_kernel<<<2048, 256, 0, stream>>>(edst, counts, rank);
  dinv_kernel<<<(NN + 255) / 256, 256, 0, stream>>>(counts, dinv);
  scan1_kernel<<<NB_SCAN, 256, 0, stream>>>(counts, offsets, blocksum);
  scan2_kernel<<<1, 512, 0, stream>>>(blocksum, blockpfx, offsets);
  scan3_kernel<<<NB_SCAN, 256, 0, stream>>>(offsets, blockpfx);
  scatter_kernel<<<2048, 256, 0, stream>>>(esrc, edst, offsets, rank, src_s);

  const int GEMM_GRID = (NN + 15) / 16;
  float* xbufs[2] = {bufA, bufB};
  const float* xcur = nullptr;
  for (int i = 0; i < 3; ++i) {
    if (i == 0) {
      // folded input linear + layer-0 weight: hbuf = (X @ Wc + bc) * dinv
      gemm64_kernel<<<GEMM_GRID, 256, 0, stream>>>(X, Wc, bc, nullptr, nullptr, nullptr,
                                                   dinv, hbuf);
    } else {
      // hbuf = (ReLU(BN_{i-1}(h2_{i-1})) @ W_i) * dinv
      gemm64_kernel<<<GEMM_GRID, 256, 0, stream>>>(xcur, Ws + (size_t)i * 64 * 64, nullptr,
                                                   gammas + (size_t)(i - 1) * 64,
                                                   betas + (size_t)(i - 1) * 64,
                                                   bnpar + (size_t)(i - 1) * 128,
                                                   dinv, hbuf);
    }
    float* xnext = xbufs[i & 1];
    agg_kernel<<<2048, 256, 0, stream>>>(hbuf, offsets, src_s, dinv,
                                         bs + (size_t)i * 64, xnext,
                                         bnacc + (size_t)i * 128);
    bn_finalize_kernel<<<1, 64, 0, stream>>>(bnacc + (size_t)i * 128, bnpar + (size_t)i * 128);
    xcur = xnext;
  }
  // xcur holds layer-2 pre-BN output
  out_kernel<<<2048, 256, 0, stream>>>(xcur, gammas + 2 * 64, betas + 2 * 64, bnpar + 2 * 128,
                                       W1, b1, W2, b2, out);
}

// Round 7
// 887.819 us; speedup vs baseline: 1.6406x; 1.0338x over previous
//
#include <hip/hip_runtime.h>

#define NN 100000
#define NE 1600000
#define NB_SCAN 391   // ceil(NN/256)

// ---------------- bf16 helpers (manual, RNE) ----------------
__device__ inline float b2f(unsigned short u) {
  return __uint_as_float(((unsigned)u) << 16);
}
__device__ inline unsigned short f2b(float f) {
  unsigned x = __float_as_uint(f);
  unsigned r = (x + 0x7fffu + ((x >> 16) & 1u)) >> 16;
  return (unsigned short)r;
}

// ---------------- CSR build ----------------

// pass 1: histogram + per-edge rank (coalesced write), atomics on counts only
__global__ void count_rank_kernel(const int* __restrict__ dst, int* __restrict__ counts,
                                  int* __restrict__ rank) {
  int i = blockIdx.x * blockDim.x + threadIdx.x;
  int st = gridDim.x * blockDim.x;
  for (; i < NE; i += st) rank[i] = atomicAdd(&counts[dst[i]], 1);
}

__global__ void scan1_kernel(const int* __restrict__ counts, int* __restrict__ offsets,
                             int* __restrict__ blocksum, float* __restrict__ dinv) {
  __shared__ int s[256];
  int t = threadIdx.x;
  int i = blockIdx.x * 256 + t;
  int v = (i < NN) ? counts[i] : 0;
  s[t] = v; __syncthreads();
  for (int off = 1; off < 256; off <<= 1) {
    int x = 0;
    if (t >= off) x = s[t - off];
    __syncthreads();
    if (t >= off) s[t] += x;
    __syncthreads();
  }
  if (i < NN) {
    offsets[i] = s[t] - v;          // exclusive within block
    dinv[i] = rsqrtf((float)v + 1.0f);
  }
  if (t == 255) blocksum[blockIdx.x] = s[255];
}

__global__ void scan2_kernel(const int* __restrict__ blocksum, int* __restrict__ blockpfx,
                             int* __restrict__ offsets) {
  __shared__ int s[512];
  int t = threadIdx.x;
  int v = (t < NB_SCAN) ? blocksum[t] : 0;
  s[t] = v; __syncthreads();
  for (int off = 1; off < 512; off <<= 1) {
    int x = 0;
    if (t >= off) x = s[t - off];
    __syncthreads();
    if (t >= off) s[t] += x;
    __syncthreads();
  }
  if (t < NB_SCAN) blockpfx[t] = s[t] - v;
  if (t == 511) offsets[NN] = s[511];         // == NE
}

__global__ void scan3_kernel(int* __restrict__ offsets, const int* __restrict__ blockpfx) {
  int i = blockIdx.x * 256 + threadIdx.x;
  if (i < NN) offsets[i] += blockpfx[i >> 8];
}

// pass 2: atomic-free scatter using precomputed ranks
__global__ void scatter_kernel(const int* __restrict__ src, const int* __restrict__ dst,
                               const int* __restrict__ offsets, const int* __restrict__ rank,
                               int* __restrict__ src_s) {
  int i = blockIdx.x * blockDim.x + threadIdx.x;
  int st = gridDim.x * blockDim.x;
  for (; i < NE; i += st) {
    int d = dst[i];
    src_s[offsets[d] + rank[i]] = src[i];
  }
}

// ---------------- fold input Linear into layer-0 weight ----------------
// Wc = W_in @ W0  (64x64), bc = b_in @ W0
__global__ void foldw_kernel(const float* __restrict__ W_in, const float* __restrict__ b_in,
                             const float* __restrict__ W0,
                             float* __restrict__ Wc, float* __restrict__ bc) {
  int t = threadIdx.x;
  for (int e = t; e < 4096; e += 256) {
    int i = e >> 6, j = e & 63;
    float s = 0.f;
#pragma unroll
    for (int k = 0; k < 64; ++k) s += W_in[i * 64 + k] * W0[k * 64 + j];
    Wc[e] = s;
  }
  if (t < 64) {
    float s = 0.f;
#pragma unroll
    for (int k = 0; k < 64; ++k) s += b_in[k] * W0[k * 64 + t];
    bc[t] = s;
  }
}

// ---------------- GEMM 64x64, fused BN-apply+ReLU on input, dinv row-scale, bf16 out ----

__global__ __launch_bounds__(256) void gemm64_kernel(
    const float* __restrict__ x, const float* __restrict__ W, const float* __restrict__ bias,
    const float* __restrict__ gamma, const float* __restrict__ beta,
    const float* __restrict__ meanistd, const float* __restrict__ rowscale,
    unsigned short* __restrict__ out16) {
  __shared__ float sW[64][64];
  __shared__ float sx[16][64];
  int t = threadIdx.x;
  int col = t & 63;
  int row0 = blockIdx.x * 16;

#pragma unroll
  for (int j = 0; j < 16; ++j) {
    int e = t + 256 * j;              // e & 63 == col
    sW[e >> 6][col] = W[e];
  }
  float g = 1.f, bt = 0.f, mn = 0.f, is = 1.f;
  if (gamma) { g = gamma[col]; bt = beta[col]; mn = meanistd[col]; is = meanistd[64 + col]; }
#pragma unroll
  for (int j = 0; j < 4; ++j) {
    int e = t + 256 * j;
    int r = e >> 6;                   // 0..15
    int grow = row0 + r;
    float v = 0.f;
    if (grow < NN) v = x[(size_t)grow * 64 + col];
    if (gamma) v = fmaxf(g * (v - mn) * is + bt, 0.f);
    sx[r][col] = v;
  }
  __syncthreads();

  int wave = t >> 6;
  float acc0 = 0, acc1 = 0, acc2 = 0, acc3 = 0;
#pragma unroll
  for (int k = 0; k < 64; ++k) {
    float wv = sW[k][col];
    acc0 += sx[wave * 4 + 0][k] * wv;
    acc1 += sx[wave * 4 + 1][k] * wv;
    acc2 += sx[wave * 4 + 2][k] * wv;
    acc3 += sx[wave * 4 + 3][k] * wv;
  }
  float bv = bias ? bias[col] : 0.f;
  int r0 = row0 + wave * 4;
#pragma unroll
  for (int r = 0; r < 4; ++r) {
    int grow = r0 + r;
    if (grow < NN) {
      float acc = (r == 0) ? acc0 : (r == 1) ? acc1 : (r == 2) ? acc2 : acc3;
      out16[(size_t)grow * 64 + col] = f2b((acc + bv) * rowscale[grow]);
    }
  }
}

// ---------------- Edge aggregation + bias + BN stats ----------------
// One node per wave (lane = channel). bf16 input rows (128 B each).
// Neighbor indices broadcast: one coalesced read of up to 64 indices, then shfl.
// Inner loop unrolled x16 -> 16 gathers in flight per wave.

__global__ __launch_bounds__(256) void agg_kernel(
    const unsigned short* __restrict__ xp16, const int* __restrict__ offsets,
    const int* __restrict__ src_s, const float* __restrict__ dinv,
    const float* __restrict__ bvec, float* __restrict__ h2,
    float* __restrict__ bnacc) {
  int t = threadIdx.x;
  int lane = t & 63;
  int wv = t >> 6;
  float bias = bvec[lane];
  float s1 = 0.f, s2 = 0.f;
  int gw = blockIdx.x * 4 + wv;
  int nw = gridDim.x * 4;
  for (int n = gw; n < NN; n += nw) {
    int beg = offsets[n], end = offsets[n + 1];
    int deg = end - beg;
    float a0 = b2f(xp16[(size_t)n * 64 + lane]);   // self term
    float a1 = 0.f, a2 = 0.f, a3 = 0.f;
    int done = 0;
    while (done < deg) {
      int chunk = deg - done;
      if (chunk > 64) chunk = 64;
      int idx = (lane < chunk) ? src_s[beg + done + lane] : 0;
      int j = 0;
      for (; j + 16 <= chunk; j += 16) {
        int t0 = __shfl(idx, j + 0), t1 = __shfl(idx, j + 1);
        int t2 = __shfl(idx, j + 2), t3 = __shfl(idx, j + 3);
        int t4 = __shfl(idx, j + 4), t5 = __shfl(idx, j + 5);
        int t6 = __shfl(idx, j + 6), t7 = __shfl(idx, j + 7);
        int t8 = __shfl(idx, j + 8), t9 = __shfl(idx, j + 9);
        int ta = __shfl(idx, j + 10), tb = __shfl(idx, j + 11);
        int tc = __shfl(idx, j + 12), td = __shfl(idx, j + 13);
        int te = __shfl(idx, j + 14), tf = __shfl(idx, j + 15);
        unsigned short u0 = xp16[(size_t)t0 * 64 + lane];
        unsigned short u1 = xp16[(size_t)t1 * 64 + lane];
        unsigned short u2 = xp16[(size_t)t2 * 64 + lane];
        unsigned short u3 = xp16[(size_t)t3 * 64 + lane];
        unsigned short u4 = xp16[(size_t)t4 * 64 + lane];
        unsigned short u5 = xp16[(size_t)t5 * 64 + lane];
        unsigned short u6 = xp16[(size_t)t6 * 64 + lane];
        unsigned short u7 = xp16[(size_t)t7 * 64 + lane];
        unsigned short u8 = xp16[(size_t)t8 * 64 + lane];
        unsigned short u9 = xp16[(size_t)t9 * 64 + lane];
        unsigned short ua = xp16[(size_t)ta * 64 + lane];
        unsigned short ub = xp16[(size_t)tb * 64 + lane];
        unsigned short uc = xp16[(size_t)tc * 64 + lane];
        unsigned short ud = xp16[(size_t)td * 64 + lane];
        unsigned short ue = xp16[(size_t)te * 64 + lane];
        unsigned short uf = xp16[(size_t)tf * 64 + lane];
        a0 += b2f(u0) + b2f(u4);  a1 += b2f(u1) + b2f(u5);
        a2 += b2f(u2) + b2f(u6);  a3 += b2f(u3) + b2f(u7);
        a0 += b2f(u8) + b2f(uc);  a1 += b2f(u9) + b2f(ud);
        a2 += b2f(ua) + b2f(ue);  a3 += b2f(ub) + b2f(uf);
      }
      for (; j + 4 <= chunk; j += 4) {
        int t0 = __shfl(idx, j + 0), t1 = __shfl(idx, j + 1);
        int t2 = __shfl(idx, j + 2), t3 = __shfl(idx, j + 3);
        a0 += b2f(xp16[(size_t)t0 * 64 + lane]);
        a1 += b2f(xp16[(size_t)t1 * 64 + lane]);
        a2 += b2f(xp16[(size_t)t2 * 64 + lane]);
        a3 += b2f(xp16[(size_t)t3 * 64 + lane]);
      }
      for (; j < chunk; ++j) {
        int s = __shfl(idx, j);
        a0 += b2f(xp16[(size_t)s * 64 + lane]);
      }
      done += chunk;
    }
    float v = ((a0 + a1) + (a2 + a3)) * dinv[n] + bias;
    h2[(size_t)n * 64 + lane] = v;
    s1 += v;
    s2 += v * v;
  }
  __shared__ float ls[4][2][64];
  ls[wv][0][lane] = s1;
  ls[wv][1][lane] = s2;
  __syncthreads();
  if (wv == 0) {
    float a = ls[0][0][lane] + ls[1][0][lane] + ls[2][0][lane] + ls[3][0][lane];
    float b = ls[0][1][lane] + ls[1][1][lane] + ls[2][1][lane] + ls[3][1][lane];
    atomicAdd(&bnacc[lane], a);
    atomicAdd(&bnacc[64 + lane], b);
  }
}

__global__ void bn_finalize_kernel(const float* __restrict__ bnacc, float* __restrict__ bnpar) {
  int c = threadIdx.x;  // 64 threads
  float mean = bnacc[c] * (1.0f / NN);
  float var = bnacc[64 + c] * (1.0f / NN) - mean * mean;
  bnpar[c] = mean;
  bnpar[64 + c] = rsqrtf(var + 1e-5f);
}

// ---------------- Output MLP: BN-apply -> Linear(64,128)+ReLU -> Linear(128,1) ----------------

__global__ __launch_bounds__(256) void out_kernel(
    const float* __restrict__ x,
    const float* __restrict__ gamma, const float* __restrict__ beta,
    const float* __restrict__ meanistd,
    const float* __restrict__ W1, const float* __restrict__ b1,
    const float* __restrict__ W2, const float* __restrict__ b2,
    float* __restrict__ out) {
  __shared__ float sW1[64][128];
  __shared__ float sW2[128];
  int t = threadIdx.x;
#pragma unroll
  for (int j = 0; j < 32; ++j) {
    int e = t + 256 * j;
    sW1[e >> 7][e & 127] = W1[e];
  }
  if (t < 128) sW2[t] = W2[t];
  __syncthreads();

  int lane = t & 63, wv = t >> 6;
  float g = gamma[lane], bt = beta[lane], mn = meanistd[lane], is = meanistd[64 + lane];
  float b1a = b1[lane], b1b = b1[64 + lane];
  float w2a = sW2[lane], w2b = sW2[64 + lane];
  float bias2 = b2[0];
  int nw = gridDim.x * 4;
  for (int row = blockIdx.x * 4 + wv; row < NN; row += nw) {
    float xv = x[(size_t)row * 64 + lane];
    xv = g * (xv - mn) * is + bt;   // last-layer BN, no ReLU
    float acc0 = 0, acc1 = 0;
#pragma unroll
    for (int k = 0; k < 64; ++k) {
      float xk = __shfl(xv, k);
      acc0 += xk * sW1[k][lane];
      acc1 += xk * sW1[k][64 + lane];
    }
    acc0 = fmaxf(acc0 + b1a, 0.f);
    acc1 = fmaxf(acc1 + b1b, 0.f);
    float p = acc0 * w2a + acc1 * w2b;
#pragma unroll
    for (int off = 32; off > 0; off >>= 1) p += __shfl_down(p, off);
    if (lane == 0) out[row] = p + bias2;
  }
}

// ---------------- launch ----------------

extern "C" void kernel_launch(void* const* d_in, const int* in_sizes, int n_in,
                              void* d_out, int out_size, void* d_ws, size_t ws_size,
                              hipStream_t stream) {
  const float* X = (const float*)d_in[0];
  const int* edge = (const int*)d_in[1];
  const int* esrc = edge;
  const int* edst = edge + NE;
  const float* W_in = (const float*)d_in[2];
  const float* b_in = (const float*)d_in[3];
  const float* Ws = (const float*)d_in[4];
  const float* bs = (const float*)d_in[5];
  const float* gammas = (const float*)d_in[6];
  const float* betas = (const float*)d_in[7];
  const float* W1 = (const float*)d_in[8];
  const float* b1 = (const float*)d_in[9];
  const float* W2 = (const float*)d_in[10];
  const float* b2 = (const float*)d_in[11];
  float* out = (float*)d_out;

  char* base = (char*)d_ws;
  size_t o = 0;
  auto alloc = [&](size_t bytes) {
    o = (o + 255) & ~(size_t)255;
    void* p = base + o;
    o += bytes;
    return p;
  };
  int* counts = (int*)alloc((size_t)NN * 4);
  int* offsets = (int*)alloc((size_t)(NN + 1) * 4);
  int* blocksum = (int*)alloc(512 * 4);
  int* blockpfx = (int*)alloc(512 * 4);
  int* rank = (int*)alloc((size_t)NE * 4);
  int* src_s = (int*)alloc((size_t)NE * 4);
  float* dinv = (float*)alloc((size_t)NN * 4);
  float* bufA = (float*)alloc((size_t)NN * 64 * 4);
  float* bufB = (float*)alloc((size_t)NN * 64 * 4);
  unsigned short* hbuf16 = (unsigned short*)alloc((size_t)NN * 64 * 2);
  float* bnacc = (float*)alloc(3 * 128 * 4);
  float* bnpar = (float*)alloc(3 * 128 * 4);
  float* Wc = (float*)alloc(4096 * 4);
  float* bc = (float*)alloc(64 * 4);

  hipMemsetAsync(counts, 0, (size_t)NN * 4, stream);
  hipMemsetAsync(bnacc, 0, 3 * 128 * 4, stream);

  foldw_kernel<<<1, 256, 0, stream>>>(W_in, b_in, Ws, Wc, bc);
  count_rank_kernel<<<2048, 256, 0, stream>>>(edst, counts, rank);
  scan1_kernel<<<NB_SCAN, 256, 0, stream>>>(counts, offsets, blocksum, dinv);
  scan2_kernel<<<1, 512, 0, stream>>>(blocksum, blockpfx, offsets);
  scan3_kernel<<<NB_SCAN, 256, 0, stream>>>(offsets, blockpfx);
  scatter_kernel<<<2048, 256, 0, stream>>>(esrc, edst, offsets, rank, src_s);

  const int GEMM_GRID = (NN + 15) / 16;
  float* xbufs[2] = {bufA, bufB};
  const float* xcur = nullptr;
  for (int i = 0; i < 3; ++i) {
    if (i == 0) {
      // folded input linear + layer-0 weight: hbuf16 = bf16((X @ Wc + bc) * dinv)
      gemm64_kernel<<<GEMM_GRID, 256, 0, stream>>>(X, Wc, bc, nullptr, nullptr, nullptr,
                                                   dinv, hbuf16);
    } else {
      // hbuf16 = bf16((ReLU(BN_{i-1}(h2_{i-1})) @ W_i) * dinv)
      gemm64_kernel<<<GEMM_GRID, 256, 0, stream>>>(xcur, Ws + (size_t)i * 64 * 64, nullptr,
                                                   gammas + (size_t)(i - 1) * 64,
                                                   betas + (size_t)(i - 1) * 64,
                                                   bnpar + (size_t)(i - 1) * 128,
                                                   dinv, hbuf16);
    }
    float* xnext = xbufs[i & 1];
    agg_kernel<<<2048, 256, 0, stream>>>(hbuf16, offsets, src_s, dinv,
                                         bs + (size_t)i * 64, xnext,
                                         bnacc + (size_t)i * 128);
    bn_finalize_kernel<<<1, 64, 0, stream>>>(bnacc + (size_t)i * 128, bnpar + (size_t)i * 128);
    xcur = xnext;
  }
  // xcur holds layer-2 pre-BN output
  out_kernel<<<2048, 256, 0, stream>>>(xcur, gammas + 2 * 64, betas + 2 * 64, bnpar + 2 * 128,
                                       W1, b1, W2, b2, out);
}

// Round 8
// 828.798 us; speedup vs baseline: 1.7574x; 1.0712x over previous
//
#include <hip/hip_runtime.h>

#define NN 100000
#define NE 1600000
#define NB_SCAN 391   // ceil(NN/256)

// ---------------- bf16 helpers (manual, RNE) ----------------
__device__ inline float b2f(unsigned short u) {
  return __uint_as_float(((unsigned)u) << 16);
}
__device__ inline unsigned short f2b(float f) {
  unsigned x = __float_as_uint(f);
  unsigned r = (x + 0x7fffu + ((x >> 16) & 1u)) >> 16;
  return (unsigned short)r;
}

// ---------------- CSR build ----------------

// pass 1: histogram + per-edge rank (coalesced write), atomics on counts only
__global__ void count_rank_kernel(const int* __restrict__ dst, int* __restrict__ counts,
                                  int* __restrict__ rank) {
  int i = blockIdx.x * blockDim.x + threadIdx.x;
  int st = gridDim.x * blockDim.x;
  for (; i < NE; i += st) rank[i] = atomicAdd(&counts[dst[i]], 1);
}

__global__ void scan1_kernel(const int* __restrict__ counts, int* __restrict__ offsets,
                             int* __restrict__ blocksum, float* __restrict__ dinv) {
  __shared__ int s[256];
  int t = threadIdx.x;
  int i = blockIdx.x * 256 + t;
  int v = (i < NN) ? counts[i] : 0;
  s[t] = v; __syncthreads();
  for (int off = 1; off < 256; off <<= 1) {
    int x = 0;
    if (t >= off) x = s[t - off];
    __syncthreads();
    if (t >= off) s[t] += x;
    __syncthreads();
  }
  if (i < NN) {
    offsets[i] = s[t] - v;          // exclusive within block
    dinv[i] = rsqrtf((float)v + 1.0f);
  }
  if (t == 255) blocksum[blockIdx.x] = s[255];
}

__global__ void scan2_kernel(const int* __restrict__ blocksum, int* __restrict__ blockpfx,
                             int* __restrict__ offsets) {
  __shared__ int s[512];
  int t = threadIdx.x;
  int v = (t < NB_SCAN) ? blocksum[t] : 0;
  s[t] = v; __syncthreads();
  for (int off = 1; off < 512; off <<= 1) {
    int x = 0;
    if (t >= off) x = s[t - off];
    __syncthreads();
    if (t >= off) s[t] += x;
    __syncthreads();
  }
  if (t < NB_SCAN) blockpfx[t] = s[t] - v;
  if (t == 511) offsets[NN] = s[511];         // == NE
}

__global__ void scan3_kernel(int* __restrict__ offsets, const int* __restrict__ blockpfx) {
  int i = blockIdx.x * 256 + threadIdx.x;
  if (i < NN) offsets[i] += blockpfx[i >> 8];
}

// pass 2: atomic-free scatter using precomputed ranks
__global__ void scatter_kernel(const int* __restrict__ src, const int* __restrict__ dst,
                               const int* __restrict__ offsets, const int* __restrict__ rank,
                               int* __restrict__ src_s) {
  int i = blockIdx.x * blockDim.x + threadIdx.x;
  int st = gridDim.x * blockDim.x;
  for (; i < NE; i += st) {
    int d = dst[i];
    src_s[offsets[d] + rank[i]] = src[i];
  }
}

// ---------------- fold input Linear into layer-0 weight ----------------
// Wc = W_in @ W0  (64x64), bc = b_in @ W0
__global__ void foldw_kernel(const float* __restrict__ W_in, const float* __restrict__ b_in,
                             const float* __restrict__ W0,
                             float* __restrict__ Wc, float* __restrict__ bc) {
  int t = threadIdx.x;
  for (int e = t; e < 4096; e += 256) {
    int i = e >> 6, j = e & 63;
    float s = 0.f;
#pragma unroll
    for (int k = 0; k < 64; ++k) s += W_in[i * 64 + k] * W0[k * 64 + j];
    Wc[e] = s;
  }
  if (t < 64) {
    float s = 0.f;
#pragma unroll
    for (int k = 0; k < 64; ++k) s += b_in[k] * W0[k * 64 + t];
    bc[t] = s;
  }
}

// ---------------- persistent matvec GEMM: 2 rows per wave-iter ----------------
// h'[row] = f2b( (act(x[row]) @ W + bias) * dinv[row] ), act = BN+ReLU if gamma.
// W staged once per block in LDS [k][lane]; row value broadcast via shfl;
// 4-way split accumulators; 2 rows share each LDS read.

__global__ __launch_bounds__(256) void gemm_mv_kernel(
    const float* __restrict__ x, const float* __restrict__ W, const float* __restrict__ bias,
    const float* __restrict__ gamma, const float* __restrict__ beta,
    const float* __restrict__ meanistd, const float* __restrict__ rowscale,
    unsigned short* __restrict__ out16) {
  __shared__ float sW[64][64];
  int t = threadIdx.x;
  int lane = t & 63;
  int wv = t >> 6;
#pragma unroll
  for (int j = 0; j < 16; ++j) {
    int e = t + 256 * j;              // e & 63 == lane
    sW[e >> 6][lane] = W[e];
  }
  __syncthreads();

  float g = 1.f, bt = 0.f, mn = 0.f, is = 1.f;
  if (gamma) { g = gamma[lane]; bt = beta[lane]; mn = meanistd[lane]; is = meanistd[64 + lane]; }
  float bv = bias ? bias[lane] : 0.f;
  int nw = gridDim.x * 4;
  // NN is even, so row pairs (r, r+1) never go out of bounds
  for (int r = (blockIdx.x * 4 + wv) * 2; r < NN; r += nw * 2) {
    float xv0 = x[(size_t)r * 64 + lane];
    float xv1 = x[(size_t)(r + 1) * 64 + lane];
    if (gamma) {
      xv0 = fmaxf(g * (xv0 - mn) * is + bt, 0.f);
      xv1 = fmaxf(g * (xv1 - mn) * is + bt, 0.f);
    }
    float p0 = bv, p1 = 0.f, p2 = 0.f, p3 = 0.f;
    float q0 = bv, q1 = 0.f, q2 = 0.f, q3 = 0.f;
#pragma unroll
    for (int k = 0; k < 64; k += 4) {
      float w0 = sW[k + 0][lane], w1 = sW[k + 1][lane];
      float w2 = sW[k + 2][lane], w3 = sW[k + 3][lane];
      p0 += __shfl(xv0, k + 0) * w0;  q0 += __shfl(xv1, k + 0) * w0;
      p1 += __shfl(xv0, k + 1) * w1;  q1 += __shfl(xv1, k + 1) * w1;
      p2 += __shfl(xv0, k + 2) * w2;  q2 += __shfl(xv1, k + 2) * w2;
      p3 += __shfl(xv0, k + 3) * w3;  q3 += __shfl(xv1, k + 3) * w3;
    }
    out16[(size_t)r * 64 + lane]       = f2b(((p0 + p1) + (p2 + p3)) * rowscale[r]);
    out16[(size_t)(r + 1) * 64 + lane] = f2b(((q0 + q1) + (q2 + q3)) * rowscale[r + 1]);
  }
}

// ---------------- Edge aggregation + bias + BN stats ----------------
// One node per wave (lane = channel). bf16 input rows (128 B each).
// Neighbor indices broadcast: one coalesced read of up to 64 indices, then shfl.
// Inner loop unrolled x16 -> 16 gathers in flight per wave.

__global__ __launch_bounds__(256) void agg_kernel(
    const unsigned short* __restrict__ xp16, const int* __restrict__ offsets,
    const int* __restrict__ src_s, const float* __restrict__ dinv,
    const float* __restrict__ bvec, float* __restrict__ h2,
    float* __restrict__ bnacc) {
  int t = threadIdx.x;
  int lane = t & 63;
  int wv = t >> 6;
  float bias = bvec[lane];
  float s1 = 0.f, s2 = 0.f;
  int gw = blockIdx.x * 4 + wv;
  int nw = gridDim.x * 4;
  for (int n = gw; n < NN; n += nw) {
    int beg = offsets[n], end = offsets[n + 1];
    int deg = end - beg;
    float a0 = b2f(xp16[(size_t)n * 64 + lane]);   // self term
    float a1 = 0.f, a2 = 0.f, a3 = 0.f;
    int done = 0;
    while (done < deg) {
      int chunk = deg - done;
      if (chunk > 64) chunk = 64;
      int idx = (lane < chunk) ? src_s[beg + done + lane] : 0;
      int j = 0;
      for (; j + 16 <= chunk; j += 16) {
        int t0 = __shfl(idx, j + 0), t1 = __shfl(idx, j + 1);
        int t2 = __shfl(idx, j + 2), t3 = __shfl(idx, j + 3);
        int t4 = __shfl(idx, j + 4), t5 = __shfl(idx, j + 5);
        int t6 = __shfl(idx, j + 6), t7 = __shfl(idx, j + 7);
        int t8 = __shfl(idx, j + 8), t9 = __shfl(idx, j + 9);
        int ta = __shfl(idx, j + 10), tb = __shfl(idx, j + 11);
        int tc = __shfl(idx, j + 12), td = __shfl(idx, j + 13);
        int te = __shfl(idx, j + 14), tf = __shfl(idx, j + 15);
        unsigned short u0 = xp16[(size_t)t0 * 64 + lane];
        unsigned short u1 = xp16[(size_t)t1 * 64 + lane];
        unsigned short u2 = xp16[(size_t)t2 * 64 + lane];
        unsigned short u3 = xp16[(size_t)t3 * 64 + lane];
        unsigned short u4 = xp16[(size_t)t4 * 64 + lane];
        unsigned short u5 = xp16[(size_t)t5 * 64 + lane];
        unsigned short u6 = xp16[(size_t)t6 * 64 + lane];
        unsigned short u7 = xp16[(size_t)t7 * 64 + lane];
        unsigned short u8 = xp16[(size_t)t8 * 64 + lane];
        unsigned short u9 = xp16[(size_t)t9 * 64 + lane];
        unsigned short ua = xp16[(size_t)ta * 64 + lane];
        unsigned short ub = xp16[(size_t)tb * 64 + lane];
        unsigned short uc = xp16[(size_t)tc * 64 + lane];
        unsigned short ud = xp16[(size_t)td * 64 + lane];
        unsigned short ue = xp16[(size_t)te * 64 + lane];
        unsigned short uf = xp16[(size_t)tf * 64 + lane];
        a0 += b2f(u0) + b2f(u4);  a1 += b2f(u1) + b2f(u5);
        a2 += b2f(u2) + b2f(u6);  a3 += b2f(u3) + b2f(u7);
        a0 += b2f(u8) + b2f(uc);  a1 += b2f(u9) + b2f(ud);
        a2 += b2f(ua) + b2f(ue);  a3 += b2f(ub) + b2f(uf);
      }
      for (; j + 4 <= chunk; j += 4) {
        int t0 = __shfl(idx, j + 0), t1 = __shfl(idx, j + 1);
        int t2 = __shfl(idx, j + 2), t3 = __shfl(idx, j + 3);
        a0 += b2f(xp16[(size_t)t0 * 64 + lane]);
        a1 += b2f(xp16[(size_t)t1 * 64 + lane]);
        a2 += b2f(xp16[(size_t)t2 * 64 + lane]);
        a3 += b2f(xp16[(size_t)t3 * 64 + lane]);
      }
      for (; j < chunk; ++j) {
        int s = __shfl(idx, j);
        a0 += b2f(xp16[(size_t)s * 64 + lane]);
      }
      done += chunk;
    }
    float v = ((a0 + a1) + (a2 + a3)) * dinv[n] + bias;
    h2[(size_t)n * 64 + lane] = v;
    s1 += v;
    s2 += v * v;
  }
  __shared__ float ls[4][2][64];
  ls[wv][0][lane] = s1;
  ls[wv][1][lane] = s2;
  __syncthreads();
  if (wv == 0) {
    float a = ls[0][0][lane] + ls[1][0][lane] + ls[2][0][lane] + ls[3][0][lane];
    float b = ls[0][1][lane] + ls[1][1][lane] + ls[2][1][lane] + ls[3][1][lane];
    atomicAdd(&bnacc[lane], a);
    atomicAdd(&bnacc[64 + lane], b);
  }
}

__global__ void bn_finalize_kernel(const float* __restrict__ bnacc, float* __restrict__ bnpar) {
  int c = threadIdx.x;  // 64 threads
  float mean = bnacc[c] * (1.0f / NN);
  float var = bnacc[64 + c] * (1.0f / NN) - mean * mean;
  bnpar[c] = mean;
  bnpar[64 + c] = rsqrtf(var + 1e-5f);
}

// ---------------- Output MLP: BN-apply -> Linear(64,128)+ReLU -> Linear(128,1) ----------------

__global__ __launch_bounds__(256) void out_kernel(
    const float* __restrict__ x,
    const float* __restrict__ gamma, const float* __restrict__ beta,
    const float* __restrict__ meanistd,
    const float* __restrict__ W1, const float* __restrict__ b1,
    const float* __restrict__ W2, const float* __restrict__ b2,
    float* __restrict__ out) {
  __shared__ float sW1[64][128];
  __shared__ float sW2[128];
  int t = threadIdx.x;
#pragma unroll
  for (int j = 0; j < 32; ++j) {
    int e = t + 256 * j;
    sW1[e >> 7][e & 127] = W1[e];
  }
  if (t < 128) sW2[t] = W2[t];
  __syncthreads();

  int lane = t & 63, wv = t >> 6;
  float g = gamma[lane], bt = beta[lane], mn = meanistd[lane], is = meanistd[64 + lane];
  float b1a = b1[lane], b1b = b1[64 + lane];
  float w2a = sW2[lane], w2b = sW2[64 + lane];
  float bias2 = b2[0];
  int nw = gridDim.x * 4;
  for (int row = blockIdx.x * 4 + wv; row < NN; row += nw) {
    float xv = x[(size_t)row * 64 + lane];
    xv = g * (xv - mn) * is + bt;   // last-layer BN, no ReLU
    float acc0 = 0, acc1 = 0;
#pragma unroll
    for (int k = 0; k < 64; ++k) {
      float xk = __shfl(xv, k);
      acc0 += xk * sW1[k][lane];
      acc1 += xk * sW1[k][64 + lane];
    }
    acc0 = fmaxf(acc0 + b1a, 0.f);
    acc1 = fmaxf(acc1 + b1b, 0.f);
    float p = acc0 * w2a + acc1 * w2b;
#pragma unroll
    for (int off = 32; off > 0; off >>= 1) p += __shfl_down(p, off);
    if (lane == 0) out[row] = p + bias2;
  }
}

// ---------------- launch ----------------

extern "C" void kernel_launch(void* const* d_in, const int* in_sizes, int n_in,
                              void* d_out, int out_size, void* d_ws, size_t ws_size,
                              hipStream_t stream) {
  const float* X = (const float*)d_in[0];
  const int* edge = (const int*)d_in[1];
  const int* esrc = edge;
  const int* edst = edge + NE;
  const float* W_in = (const float*)d_in[2];
  const float* b_in = (const float*)d_in[3];
  const float* Ws = (const float*)d_in[4];
  const float* bs = (const float*)d_in[5];
  const float* gammas = (const float*)d_in[6];
  const float* betas = (const float*)d_in[7];
  const float* W1 = (const float*)d_in[8];
  const float* b1 = (const float*)d_in[9];
  const float* W2 = (const float*)d_in[10];
  const float* b2 = (const float*)d_in[11];
  float* out = (float*)d_out;

  char* base = (char*)d_ws;
  size_t o = 0;
  auto alloc = [&](size_t bytes) {
    o = (o + 255) & ~(size_t)255;
    void* p = base + o;
    o += bytes;
    return p;
  };
  int* counts = (int*)alloc((size_t)NN * 4);
  int* offsets = (int*)alloc((size_t)(NN + 1) * 4);
  int* blocksum = (int*)alloc(512 * 4);
  int* blockpfx = (int*)alloc(512 * 4);
  int* rank = (int*)alloc((size_t)NE * 4);
  int* src_s = (int*)alloc((size_t)NE * 4);
  float* dinv = (float*)alloc((size_t)NN * 4);
  float* bufA = (float*)alloc((size_t)NN * 64 * 4);
  float* bufB = (float*)alloc((size_t)NN * 64 * 4);
  unsigned short* hbuf16 = (unsigned short*)alloc((size_t)NN * 64 * 2);
  float* bnacc = (float*)alloc(3 * 128 * 4);
  float* bnpar = (float*)alloc(3 * 128 * 4);
  float* Wc = (float*)alloc(4096 * 4);
  float* bc = (float*)alloc(64 * 4);

  hipMemsetAsync(counts, 0, (size_t)NN * 4, stream);
  hipMemsetAsync(bnacc, 0, 3 * 128 * 4, stream);

  foldw_kernel<<<1, 256, 0, stream>>>(W_in, b_in, Ws, Wc, bc);
  count_rank_kernel<<<2048, 256, 0, stream>>>(edst, counts, rank);
  scan1_kernel<<<NB_SCAN, 256, 0, stream>>>(counts, offsets, blocksum, dinv);
  scan2_kernel<<<1, 512, 0, stream>>>(blocksum, blockpfx, offsets);
  scan3_kernel<<<NB_SCAN, 256, 0, stream>>>(offsets, blockpfx);
  scatter_kernel<<<2048, 256, 0, stream>>>(esrc, edst, offsets, rank, src_s);

  float* xbufs[2] = {bufA, bufB};
  const float* xcur = nullptr;
  for (int i = 0; i < 3; ++i) {
    if (i == 0) {
      // folded input linear + layer-0 weight: hbuf16 = bf16((X @ Wc + bc) * dinv)
      gemm_mv_kernel<<<2048, 256, 0, stream>>>(X, Wc, bc, nullptr, nullptr, nullptr,
                                               dinv, hbuf16);
    } else {
      // hbuf16 = bf16((ReLU(BN_{i-1}(h2_{i-1})) @ W_i) * dinv)
      gemm_mv_kernel<<<2048, 256, 0, stream>>>(xcur, Ws + (size_t)i * 64 * 64, nullptr,
                                               gammas + (size_t)(i - 1) * 64,
                                               betas + (size_t)(i - 1) * 64,
                                               bnpar + (size_t)(i - 1) * 128,
                                               dinv, hbuf16);
    }
    float* xnext = xbufs[i & 1];
    agg_kernel<<<2048, 256, 0, stream>>>(hbuf16, offsets, src_s, dinv,
                                         bs + (size_t)i * 64, xnext,
                                         bnacc + (size_t)i * 128);
    bn_finalize_kernel<<<1, 64, 0, stream>>>(bnacc + (size_t)i * 128, bnpar + (size_t)i * 128);
    xcur = xnext;
  }
  // xcur holds layer-2 pre-BN output
  out_kernel<<<2048, 256, 0, stream>>>(xcur, gammas + 2 * 64, betas + 2 * 64, bnpar + 2 * 128,
                                       W1, b1, W2, b2, out);
}